// Round 8
// baseline (605.035 us; speedup 1.0000x reference)
//
#include <hip/hip_runtime.h>
#include <stdint.h>

#define LM1  127
#define NTHR 512

typedef _Float16 half8_t __attribute__((ext_vector_type(8)));
typedef _Float16 half4_t __attribute__((ext_vector_type(4)));
typedef float    f32x4   __attribute__((ext_vector_type(4)));

__device__ __forceinline__ float fast_tanh(float x) {
  float e = __expf(2.0f * x);
  return 1.0f - 2.0f * __builtin_amdgcn_rcpf(e + 1.0f);
}

// Round-8 = round-7 with ONE change: the kc cross-lane combine uses
// __shfl_xor(p,16) (primitive verified in round 0) instead of the
// never-verified v_permlane16_swap_b32 asm. Everything else identical.
//   GEMM1: h^T = W1^T @ z^T  (A = W1^T frags in regs, 1 M-tile/wave: hcols
//          [16w,16w+16); B = z^T from zsbT). Output packs into hA (B-frag
//          layout of h^T) with ONE ds_write_b64 per lane.
//   GEMM2: f^T = W2^T @ h^T  (A = W2^T frags in regs, 4 M-tiles/wave: fcols
//          [64w,64w+64); B = h^T from hA). Lane (lq,l15) holds f[l15][64w+
//          16mt+4lq+reg] in regs -> kc = 4 in-lane tanh*g + one lane^16
//          exchange (partner holds the other c-quad for the same h).
// fwb is DELETED; kc VALU runs in the shadow of other M-tiles' MFMAs.
// zsbT layout: z[r][h] at half-index 128*(h>>3) + 8*r + (h&7), dbuf; rows
// 4..15 zero-init and never written. kc owners: (r=l15<4, h=8w+2mt+lqh);
// dedup writer: lane lql writes mt in {2lql, 2lql+1}, delta(mt) = 2mt+lqh.
#define BAR() asm volatile("s_waitcnt lgkmcnt(0)\n\ts_barrier" ::: "memory")

__global__ void __launch_bounds__(NTHR, 2) cde_kernel(
    const float* __restrict__ coeffs,
    const float* __restrict__ Wi1, const float* __restrict__ bi1,
    const float* __restrict__ Wi2, const float* __restrict__ bi2,
    const float* __restrict__ W1,  const float* __restrict__ b1,
    const float* __restrict__ W2,  const float* __restrict__ b2,
    float* __restrict__ out)
{
  __shared__ __align__(16) _Float16 zsbT[2][1024];   // 4 KB: z^T B-frag, dbuf
  __shared__ __align__(16) _Float16 hA[2048];        // 4 KB: h^T B-frag
  __shared__ __align__(16) float    gds[2][3][4][8]; // dXdt at fr=0,.5,1 (dbuf)

  const int t    = threadIdx.x;
  const int lane = t & 63;
  const int w    = t >> 6;            // wave 0..7
  const int l15  = lane & 15;
  const int lq   = lane >> 4;
  const int lqh  = lq >> 1, lql = lq & 1;
  const int r4   = l15 & 3;           // clamped batch row (for addresses)
  const bool rowok = (l15 < 4);
  const int row0 = blockIdx.x * 4;

  // zero zsbT (both buffers); rows 4..15 stay zero forever
  for (int u = t; u < 1024; u += NTHR) ((uint32_t*)zsbT)[u] = 0u;

  // ---- GEMM1 A-frags: W1^T, wave M-tile = hcols [16w, 16w+16)
  half8_t wA[2];
  #pragma unroll
  for (int kt = 0; kt < 2; ++kt)
    #pragma unroll
    for (int j = 0; j < 8; ++j)
      wA[kt][j] = (_Float16)W1[(1 + 32 * kt + 8 * lq + j) * 128 + 16 * w + l15];

  // u-constants: hcols 16w+4lq+reg
  f32x4 w1t4, b14;
  #pragma unroll
  for (int reg = 0; reg < 4; ++reg) {
    w1t4[reg] = W1[16 * w + 4 * lq + reg];
    b14[reg]  = b1[16 * w + 4 * lq + reg];
  }

  // ---- GEMM2 A-frags: W2^T, 4 M-tiles = fcols [64w, 64w+64)
  half8_t wf[4][4];
  #pragma unroll
  for (int mt = 0; mt < 4; ++mt)
    #pragma unroll
    for (int kt = 0; kt < 4; ++kt)
      #pragma unroll
      for (int j = 0; j < 8; ++j)
        wf[mt][kt][j] =
            (_Float16)W2[(32 * kt + 8 * lq + j) * 512 + 64 * w + 16 * mt + l15];

  // ---- b2 per lane: fcols 64w+16mt+4lq+reg
  f32x4 b2v[4];
  #pragma unroll
  for (int mt = 0; mt < 4; ++mt)
    b2v[mt] = *(const f32x4*)&b2[64 * w + 16 * mt + 4 * lq];

  // hA write base: hcols 16w+4lq+{0..3}, batch l15 (b64)
  _Float16* const hwp = &hA[128 * (2 * w + lqh) + 8 * l15 + 4 * lql];
  // zsbT dedup write offsets: mtA=2*lql (delta dA), mtB=2*lql+1 (delta dB)
  const int zbase = 128 * w + 8 * l15;
  const int dA = 4 * lql + lqh;
  const int dB = 4 * lql + 2 + lqh;

  // ---- z0 for this lane's 4 (mt) chains: (r=l15, h=8w+2mt+lqh)
  float z[4];
  {
    const float* cb = coeffs + (size_t)(row0 + r4) * (LM1 * 32);
    float x0[8];
    #pragma unroll
    for (int c = 0; c < 8; ++c) x0[c] = cb[c];
    float acc[4];
    #pragma unroll
    for (int mt = 0; mt < 4; ++mt) acc[mt] = bi2[8 * w + 2 * mt + lqh];
    for (int j = 0; j < 20; ++j) {
      float uj = bi1[j];
      #pragma unroll
      for (int c = 0; c < 8; ++c) uj += x0[c] * Wi1[c * 20 + j];
      uj = fmaxf(uj, 0.0f);
      #pragma unroll
      for (int mt = 0; mt < 4; ++mt) acc[mt] += uj * Wi2[j * 64 + 8 * w + 2 * mt + lqh];
    }
    #pragma unroll
    for (int mt = 0; mt < 4; ++mt) z[mt] = fast_tanh(acc[mt]);
  }
  if (rowok) {
    const float zA = lql ? z[2] : z[0];
    const float zB = lql ? z[3] : z[1];
    zsbT[0][zbase + dA] = (_Float16)zA;
    zsbT[0][zbase + dB] = (_Float16)zB;
    float* op = out + (size_t)(row0 + l15) * 8192 + 8 * w;
    op[dA] = zA;
    op[dB] = zB;
  }

  // ---- coeff prefetch / gds staging on wave 7 (R3-proven)
  const int rg = (lane >> 3) & 3, cg = lane & 7;
  const float* cbp = coeffs + (size_t)(row0 + rg) * (LM1 * 32);
  float pb = 0.f, pc = 0.f, pd = 0.f, pbn = 0.f;
  const bool stg = (w == 7) && (lane < 32);
  if (stg) { pb = cbp[8 + cg]; pc = cbp[16 + cg]; pd = cbp[24 + cg]; pbn = cbp[40 + cg]; }

  __syncthreads();   // init complete

  for (int i = 0; i < LM1; ++i) {
    if (stg) {
      gds[i & 1][0][rg][cg] = pb;
      gds[i & 1][1][rg][cg] = pb + pc + 0.75f * pd;
      gds[i & 1][2][rg][cg] = (i < LM1 - 1) ? pbn : fmaf(3.0f, pd, fmaf(2.0f, pc, pb));
      if (i + 1 < LM1) {
        const float* nb = cbp + (size_t)(i + 1) * 32;
        pb = nb[8 + cg]; pc = nb[16 + cg]; pd = nb[24 + cg];
        pbn = (i + 2 < LM1) ? nb[40 + cg] : 0.0f;
      }
    }

    float ksum[4] = {0.f, 0.f, 0.f, 0.f};
    #pragma unroll
    for (int s = 0; s < 4; ++s) {
      const int   rb = s & 1, wb = rb ^ 1;
      const int   gi = (s == 0) ? 0 : (s == 3) ? 2 : 1;
      const float ts = (float)i + ((s == 0) ? 0.0f : (s == 3) ? 1.0f : 0.5f);

      // ---- GEMM1 (swapped): h^T tile for hcols [16w,16w+16)
      const half8_t zb0 = *(const half8_t*)(&zsbT[rb][8 * lane]);
      const half8_t zb1 = *(const half8_t*)(&zsbT[rb][512 + 8 * lane]);
      f32x4 hd = {0.f, 0.f, 0.f, 0.f};
      hd = __builtin_amdgcn_mfma_f32_16x16x32_f16(wA[0], zb0, hd, 0, 0, 0);
      hd = __builtin_amdgcn_mfma_f32_16x16x32_f16(wA[1], zb1, hd, 0, 0, 0);
      half4_t hv;
      hv[0] = (_Float16)fmaxf(hd.x + fmaf(ts, w1t4.x, b14.x), 0.0f);
      hv[1] = (_Float16)fmaxf(hd.y + fmaf(ts, w1t4.y, b14.y), 0.0f);
      hv[2] = (_Float16)fmaxf(hd.z + fmaf(ts, w1t4.z, b14.z), 0.0f);
      hv[3] = (_Float16)fmaxf(hd.w + fmaf(ts, w1t4.w, b14.w), 0.0f);
      *(half4_t*)hwp = hv;
      BAR();   // hA visible

      // ---- GEMM2 (swapped) + fused in-register kc
      const f32x4 gv = *(const f32x4*)&gds[i & 1][gi][r4][4 * lql];
      half8_t hb[4];
      #pragma unroll
      for (int kt = 0; kt < 4; ++kt)
        hb[kt] = *(const half8_t*)(&hA[512 * kt + 8 * lane]);
      f32x4 d0 = {0.f, 0.f, 0.f, 0.f}, d1 = d0, d2 = d0, d3 = d0;
      #pragma unroll
      for (int kt = 0; kt < 4; ++kt) {
        d0 = __builtin_amdgcn_mfma_f32_16x16x32_f16(wf[0][kt], hb[kt], d0, 0, 0, 0);
        d1 = __builtin_amdgcn_mfma_f32_16x16x32_f16(wf[1][kt], hb[kt], d1, 0, 0, 0);
        d2 = __builtin_amdgcn_mfma_f32_16x16x32_f16(wf[2][kt], hb[kt], d2, 0, 0, 0);
        d3 = __builtin_amdgcn_mfma_f32_16x16x32_f16(wf[3][kt], hb[kt], d3, 0, 0, 0);
      }
      const float p0 = fast_tanh(d0.x + b2v[0].x) * gv.x + fast_tanh(d0.y + b2v[0].y) * gv.y
                     + fast_tanh(d0.z + b2v[0].z) * gv.z + fast_tanh(d0.w + b2v[0].w) * gv.w;
      const float p1 = fast_tanh(d1.x + b2v[1].x) * gv.x + fast_tanh(d1.y + b2v[1].y) * gv.y
                     + fast_tanh(d1.z + b2v[1].z) * gv.z + fast_tanh(d1.w + b2v[1].w) * gv.w;
      const float p2 = fast_tanh(d2.x + b2v[2].x) * gv.x + fast_tanh(d2.y + b2v[2].y) * gv.y
                     + fast_tanh(d2.z + b2v[2].z) * gv.z + fast_tanh(d2.w + b2v[2].w) * gv.w;
      const float p3 = fast_tanh(d3.x + b2v[3].x) * gv.x + fast_tanh(d3.y + b2v[3].y) * gv.y
                     + fast_tanh(d3.z + b2v[3].z) * gv.z + fast_tanh(d3.w + b2v[3].w) * gv.w;
      // lane^16 partner holds the other c-quad for the same h (pair-add is
      // commutative bit-exactly, so redundant lql-chains stay identical)
      const float kcv0 = p0 + __shfl_xor(p0, 16, 64);
      const float kcv1 = p1 + __shfl_xor(p1, 16, 64);
      const float kcv2 = p2 + __shfl_xor(p2, 16, 64);
      const float kcv3 = p3 + __shfl_xor(p3, 16, 64);
      const float wgt = (s == 1 || s == 2) ? 2.0f : 1.0f;
      ksum[0] += wgt * kcv0;
      ksum[1] += wgt * kcv1;
      ksum[2] += wgt * kcv2;
      ksum[3] += wgt * kcv3;

      if (s < 3) {
        const float cn = (s == 2) ? 1.0f : 0.5f;
        if (rowok) {
          const float zA = lql ? z[2] : z[0], kA = lql ? kcv2 : kcv0;
          const float zB = lql ? z[3] : z[1], kB = lql ? kcv3 : kcv1;
          zsbT[wb][zbase + dA] = (_Float16)fmaf(cn, kA, zA);
          zsbT[wb][zbase + dB] = (_Float16)fmaf(cn, kB, zB);
        }
      } else {
        z[0] = fmaf(ksum[0], 1.0f / 6.0f, z[0]);
        z[1] = fmaf(ksum[1], 1.0f / 6.0f, z[1]);
        z[2] = fmaf(ksum[2], 1.0f / 6.0f, z[2]);
        z[3] = fmaf(ksum[3], 1.0f / 6.0f, z[3]);
        if (rowok) {
          const float zA = lql ? z[2] : z[0];
          const float zB = lql ? z[3] : z[1];
          zsbT[wb][zbase + dA] = (_Float16)zA;
          zsbT[wb][zbase + dB] = (_Float16)zB;
          float* op = out + (size_t)(row0 + l15) * 8192 + (size_t)(i + 1) * 64 + 8 * w;
          op[dA] = zA;   // fire-and-forget
          op[dB] = zB;
        }
      }
      BAR();   // zsbT[wb] visible for next sub-stage
    }
  }
}

extern "C" void kernel_launch(void* const* d_in, const int* in_sizes, int n_in,
                              void* d_out, int out_size, void* d_ws, size_t ws_size,
                              hipStream_t stream) {
  const float* coeffs = (const float*)d_in[0];
  const float* Wi1    = (const float*)d_in[1];
  const float* bi1    = (const float*)d_in[2];
  const float* Wi2    = (const float*)d_in[3];
  const float* bi2    = (const float*)d_in[4];
  const float* W1     = (const float*)d_in[5];
  const float* b1     = (const float*)d_in[6];
  const float* W2     = (const float*)d_in[7];
  const float* b2     = (const float*)d_in[8];
  float* out          = (float*)d_out;
  (void)in_sizes; (void)n_in; (void)out_size; (void)d_ws; (void)ws_size;
  cde_kernel<<<256, NTHR, 0, stream>>>(coeffs, Wi1, bi1, Wi2, bi2,
                                       W1, b1, W2, b2, out);
}